// Round 1
// baseline (6921.700 us; speedup 1.0000x reference)
//
#include <hip/hip_runtime.h>
#include <math.h>

// Problem constants
#define B 64
#define NN 49
#define ENC 2048
#define DEC 512
#define ATT 512
#define EMB 300
#define VOC 10000
#define TT 30

__device__ __forceinline__ float fast_tanh(float x) {
    float e = __expf(2.f * x);
    return 1.f - 2.f / (e + 1.f);
}
__device__ __forceinline__ float sigmoidf(float x) {
    return 1.f / (1.f + __expf(-x));
}

// ---------------------------------------------------------------------------
// Generic f32 NT GEMM: C[M,N] = A[M,K] @ B[N,K]^T (+ bias[N])
// mode 0: C row-major ldc. mode 1: preds scatter C[b*T*V + t*V + v], r=t*64+b
// ---------------------------------------------------------------------------
__global__ __launch_bounds__(256) void gemm_nt(
    const float* __restrict__ A, int lda,
    const float* __restrict__ Bm, int ldb,
    const float* __restrict__ bias,
    float* __restrict__ C, int ldc,
    int M, int N, int K, int mode)
{
    const int tid = threadIdx.x;
    const int tx = tid & 15, ty = tid >> 4;
    const int m0 = blockIdx.y * 64, n0 = blockIdx.x * 64;
    __shared__ float As[16][64];
    __shared__ float Bs[16][64];
    float acc[4][4] = {};
    const int lrow = tid >> 2;
    const int lk = (tid & 3) * 4;
    const int nK = (K + 15) >> 4;
    for (int c = 0; c < nK; ++c) {
        const int kk = c * 16 + lk;
        // A tile (M always a multiple of 64 in our uses)
        {
            float4 v = {0.f, 0.f, 0.f, 0.f};
            const float* p = A + (size_t)(m0 + lrow) * lda + kk;
            if (kk + 3 < K) v = *(const float4*)p;
            else {
                if (kk + 0 < K) v.x = p[0];
                if (kk + 1 < K) v.y = p[1];
                if (kk + 2 < K) v.z = p[2];
                if (kk + 3 < K) v.w = p[3];
            }
            As[lk + 0][lrow] = v.x; As[lk + 1][lrow] = v.y;
            As[lk + 2][lrow] = v.z; As[lk + 3][lrow] = v.w;
        }
        // B tile
        {
            float4 v = {0.f, 0.f, 0.f, 0.f};
            const int col = n0 + lrow;
            if (col < N) {
                const float* p = Bm + (size_t)col * ldb + kk;
                if (kk + 3 < K) v = *(const float4*)p;
                else {
                    if (kk + 0 < K) v.x = p[0];
                    if (kk + 1 < K) v.y = p[1];
                    if (kk + 2 < K) v.z = p[2];
                    if (kk + 3 < K) v.w = p[3];
                }
            }
            Bs[lk + 0][lrow] = v.x; Bs[lk + 1][lrow] = v.y;
            Bs[lk + 2][lrow] = v.z; Bs[lk + 3][lrow] = v.w;
        }
        __syncthreads();
        #pragma unroll
        for (int k = 0; k < 16; ++k) {
            float4 a = *(const float4*)&As[k][ty * 4];
            float4 b = *(const float4*)&Bs[k][tx * 4];
            acc[0][0] += a.x * b.x; acc[0][1] += a.x * b.y; acc[0][2] += a.x * b.z; acc[0][3] += a.x * b.w;
            acc[1][0] += a.y * b.x; acc[1][1] += a.y * b.y; acc[1][2] += a.y * b.z; acc[1][3] += a.y * b.w;
            acc[2][0] += a.z * b.x; acc[2][1] += a.z * b.y; acc[2][2] += a.z * b.z; acc[2][3] += a.z * b.w;
            acc[3][0] += a.w * b.x; acc[3][1] += a.w * b.y; acc[3][2] += a.w * b.z; acc[3][3] += a.w * b.w;
        }
        __syncthreads();
    }
    #pragma unroll
    for (int i = 0; i < 4; ++i) {
        const int r = m0 + ty * 4 + i;
        if (r >= M) continue;
        #pragma unroll
        for (int j = 0; j < 4; ++j) {
            const int cN = n0 + tx * 4 + j;
            if (cN >= N) continue;
            float val = acc[i][j] + (bias ? bias[cN] : 0.f);
            if (mode == 0) C[(size_t)r * ldc + cN] = val;
            else {
                const int t = r >> 6, bb = r & 63;
                C[(size_t)bb * (TT * VOC) + (size_t)t * VOC + cN] = val;
            }
        }
    }
}

// ---------------------------------------------------------------------------
// mean over N of features -> mean_f [B, ENC]
// ---------------------------------------------------------------------------
__global__ __launch_bounds__(256) void k_mean(const float* __restrict__ f,
                                              float* __restrict__ mean_f)
{
    const int b = blockIdx.x;
    for (int e = threadIdx.x; e < ENC; e += 256) {
        float s = 0.f;
        for (int n = 0; n < NN; ++n) s += f[(size_t)(b * NN + n) * ENC + e];
        mean_f[(size_t)b * ENC + e] = s * (1.f / 49.f);
    }
}

// ---------------------------------------------------------------------------
// embedding gather: embeds[r=t*64+b, :] = emb[captions[b, t], :]
// ---------------------------------------------------------------------------
__global__ __launch_bounds__(256) void k_embed(const int* __restrict__ cap,
                                               const float* __restrict__ emb,
                                               float* __restrict__ embeds)
{
    const int r = blockIdx.x;
    const int t = r >> 6, b = r & 63;
    const int c = cap[b * 31 + t];
    for (int j = threadIdx.x; j < EMB; j += 256)
        embeds[(size_t)r * EMB + j] = emb[(size_t)c * EMB + j];
}

// ---------------------------------------------------------------------------
// gates partial GEMM, split-K: grid (32 colblocks, 16 kslices)
// A = [context | h] (64 x 2560 logical), B rows j: [ih_w[j,300:2348] | hh_w[j,:]]
// gpart[ks][b][j] = partial sums (no bias)
// ---------------------------------------------------------------------------
__global__ __launch_bounds__(256) void k_gates(
    const float* __restrict__ ctx,   // [64][2048]
    const float* __restrict__ h,     // [64][512]
    const float* __restrict__ ih_w,  // [2048][2348]
    const float* __restrict__ hh_w,  // [2048][512]
    float* __restrict__ gpart)       // [16][64][2048]
{
    const int tid = threadIdx.x;
    const int tx = tid & 15, ty = tid >> 4;
    const int j0 = blockIdx.x * 64;
    const int ks = blockIdx.y;
    __shared__ float As[16][64];
    __shared__ float Bs[16][64];
    float acc[4][4] = {};
    const int lrow = tid >> 2;
    const int lk = (tid & 3) * 4;
    for (int c = 0; c < 10; ++c) {
        const int kk = ks * 160 + c * 16 + lk;
        float4 av, bv;
        if (kk < 2048) av = *(const float4*)(ctx + (size_t)lrow * 2048 + kk);
        else           av = *(const float4*)(h + (size_t)lrow * 512 + (kk - 2048));
        const int j = j0 + lrow;
        if (kk < 2048) bv = *(const float4*)(ih_w + (size_t)j * 2348 + 300 + kk);
        else           bv = *(const float4*)(hh_w + (size_t)j * 512 + (kk - 2048));
        As[lk + 0][lrow] = av.x; As[lk + 1][lrow] = av.y;
        As[lk + 2][lrow] = av.z; As[lk + 3][lrow] = av.w;
        Bs[lk + 0][lrow] = bv.x; Bs[lk + 1][lrow] = bv.y;
        Bs[lk + 2][lrow] = bv.z; Bs[lk + 3][lrow] = bv.w;
        __syncthreads();
        #pragma unroll
        for (int k = 0; k < 16; ++k) {
            float4 a = *(const float4*)&As[k][ty * 4];
            float4 b = *(const float4*)&Bs[k][tx * 4];
            acc[0][0] += a.x * b.x; acc[0][1] += a.x * b.y; acc[0][2] += a.x * b.z; acc[0][3] += a.x * b.w;
            acc[1][0] += a.y * b.x; acc[1][1] += a.y * b.y; acc[1][2] += a.y * b.z; acc[1][3] += a.y * b.w;
            acc[2][0] += a.z * b.x; acc[2][1] += a.z * b.y; acc[2][2] += a.z * b.z; acc[2][3] += a.z * b.w;
            acc[3][0] += a.w * b.x; acc[3][1] += a.w * b.y; acc[3][2] += a.w * b.z; acc[3][3] += a.w * b.w;
        }
        __syncthreads();
    }
    #pragma unroll
    for (int i = 0; i < 4; ++i) {
        const int r = ty * 4 + i;  // batch b
        #pragma unroll
        for (int j = 0; j < 4; ++j) {
            gpart[(size_t)(ks * 64 + r) * 2048 + j0 + tx * 4 + j] = acc[i][j];
        }
    }
}

// ---------------------------------------------------------------------------
// Per-batch step kernel: [pointwise LSTM of previous gates] + w_ah + scores +
// softmax + context. One block per b.
// ---------------------------------------------------------------------------
__global__ __launch_bounds__(256) void k_att(
    const float* __restrict__ features,
    const float* __restrict__ u_hs,
    const float* __restrict__ W_w, const float* __restrict__ W_b,
    const float* __restrict__ A_w, const float* __restrict__ A_b,
    const float* __restrict__ pre_x,
    const float* __restrict__ hh_b,
    const float* __restrict__ gpart,
    float* __restrict__ h_cur, float* __restrict__ c_cur,
    float* __restrict__ ctx, float* __restrict__ Hall,
    float* __restrict__ alphas,
    int s, int do_point, int do_attn)
{
    const int b = blockIdx.x;
    const int tid = threadIdx.x;
    __shared__ float h_lds[512];
    __shared__ float wah[512];
    __shared__ float awl[512];
    __shared__ float red[64];

    if (do_point) {
        const int sp = s - 1;
        for (int d = tid; d < 512; d += 256) {
            float g4[4];
            #pragma unroll
            for (int q = 0; q < 4; ++q) {
                const int j = q * 512 + d;
                float a = pre_x[(size_t)(sp * 64 + b) * 2048 + j] + hh_b[j];
                for (int ksl = 0; ksl < 16; ++ksl)
                    a += gpart[(size_t)(ksl * 64 + b) * 2048 + j];
                g4[q] = a;
            }
            const float ig = sigmoidf(g4[0]);
            const float fg = sigmoidf(g4[1]);
            const float gg = fast_tanh(g4[2]);
            const float og = sigmoidf(g4[3]);
            const float cv = fg * c_cur[b * 512 + d] + ig * gg;
            const float hv = og * fast_tanh(cv);
            c_cur[b * 512 + d] = cv;
            h_cur[b * 512 + d] = hv;
            Hall[(size_t)(sp * 64 + b) * 512 + d] = hv;
            h_lds[d] = hv;
        }
    } else {
        for (int d = tid; d < 512; d += 256) h_lds[d] = h_cur[b * 512 + d];
    }
    if (!do_attn) return;

    for (int a = tid; a < 512; a += 256) awl[a] = A_w[a];
    __syncthreads();

    // w_ah = h @ W_w^T + W_b   (per-b GEMV, rows of W_w contiguous)
    for (int a = tid; a < 512; a += 256) {
        const float4* wr = (const float4*)(W_w + (size_t)a * 512);
        float acc = W_b[a];
        #pragma unroll 4
        for (int k4 = 0; k4 < 128; ++k4) {
            const float4 w = wr[k4];
            const int k = k4 * 4;
            acc += h_lds[k] * w.x + h_lds[k + 1] * w.y + h_lds[k + 2] * w.z + h_lds[k + 3] * w.w;
        }
        wah[a] = acc;
    }
    __syncthreads();

    // scores[n] = sum_a A_w[a] * tanh(u_hs[b,n,a] + wah[a]) + A_b
    const int lane = tid & 63, wid = tid >> 6;
    for (int n = wid; n < NN; n += 4) {
        const float* up = u_hs + (size_t)(b * NN + n) * 512;
        float acc = 0.f;
        for (int a = lane; a < 512; a += 64)
            acc += awl[a] * fast_tanh(up[a] + wah[a]);
        #pragma unroll
        for (int m = 32; m; m >>= 1) acc += __shfl_xor(acc, m, 64);
        if (lane == 0) red[n] = acc + A_b[0];
    }
    __syncthreads();

    // softmax over 49 (wave 0)
    if (tid < 64) {
        const float sc = (tid < NN) ? red[tid] : -1e30f;
        float mx = sc;
        #pragma unroll
        for (int m = 32; m; m >>= 1) mx = fmaxf(mx, __shfl_xor(mx, m, 64));
        float e = (tid < NN) ? __expf(sc - mx) : 0.f;
        float sum = e;
        #pragma unroll
        for (int m = 32; m; m >>= 1) sum += __shfl_xor(sum, m, 64);
        const float al = e / sum;
        if (tid < NN) {
            red[tid] = al;
            alphas[(size_t)b * (TT * NN) + (size_t)s * NN + tid] = al;
        }
    }
    __syncthreads();

    // context[e] = sum_n alpha[n] * features[b,n,e]
    for (int e = tid; e < ENC; e += 256) {
        float acc = 0.f;
        #pragma unroll
        for (int n = 0; n < NN; ++n)
            acc += red[n] * features[(size_t)(b * NN + n) * ENC + e];
        ctx[(size_t)b * ENC + e] = acc;
    }
}

// ---------------------------------------------------------------------------
extern "C" void kernel_launch(void* const* d_in, const int* in_sizes, int n_in,
                              void* d_out, int out_size, void* d_ws, size_t ws_size,
                              hipStream_t stream)
{
    const float* features = (const float*)d_in[0];
    const int*   captions = (const int*)d_in[1];
    const float* emb      = (const float*)d_in[2];
    const float* U_w      = (const float*)d_in[3];
    const float* U_b      = (const float*)d_in[4];
    const float* W_w      = (const float*)d_in[5];
    const float* W_b      = (const float*)d_in[6];
    const float* A_w      = (const float*)d_in[7];
    const float* A_b      = (const float*)d_in[8];
    const float* iH_w     = (const float*)d_in[9];
    const float* iH_b     = (const float*)d_in[10];
    const float* iC_w     = (const float*)d_in[11];
    const float* iC_b     = (const float*)d_in[12];
    const float* ih_w     = (const float*)d_in[13];
    const float* ih_b     = (const float*)d_in[14];
    const float* hh_w     = (const float*)d_in[15];
    const float* hh_b     = (const float*)d_in[16];
    const float* fcn_w    = (const float*)d_in[17];
    const float* fcn_b    = (const float*)d_in[18];

    float* out    = (float*)d_out;
    float* alphas = out + (size_t)B * TT * VOC;  // 19,200,000

    float* ws     = (float*)d_ws;
    float* mean_f = ws;                       // 64*2048      = 131072
    float* h_cur  = mean_f + 131072;          // 64*512       = 32768
    float* c_cur  = h_cur + 32768;            // 32768
    float* ctxb   = c_cur + 32768;            // 64*2048      = 131072
    float* embeds = ctxb + 131072;            // 1920*300     = 576000
    float* u_hs   = embeds + 576000;          // 3136*512     = 1605632
    float* pre_x  = u_hs + 1605632;           // 1920*2048    = 3932160
    float* Hall   = pre_x + 3932160;          // 1920*512     = 983040
    float* gpart  = Hall + 983040;            // 16*64*2048   = 2097152

    // init hidden state
    k_mean<<<64, 256, 0, stream>>>(features, mean_f);
    gemm_nt<<<dim3(8, 1), 256, 0, stream>>>(mean_f, ENC, iH_w, ENC, iH_b, h_cur, DEC, 64, DEC, ENC, 0);
    gemm_nt<<<dim3(8, 1), 256, 0, stream>>>(mean_f, ENC, iC_w, ENC, iC_b, c_cur, DEC, 64, DEC, ENC, 0);

    // hoisted precomputes
    k_embed<<<1920, 256, 0, stream>>>(captions, emb, embeds);
    gemm_nt<<<dim3(8, 49), 256, 0, stream>>>(features, ENC, U_w, ENC, U_b, u_hs, ATT, B * NN, ATT, ENC, 0);
    gemm_nt<<<dim3(32, 30), 256, 0, stream>>>(embeds, EMB, ih_w, 2348, ih_b, pre_x, 2048, TT * B, 2048, EMB, 0);

    // recurrence
    for (int s = 0; s < TT; ++s) {
        k_att<<<64, 256, 0, stream>>>(features, u_hs, W_w, W_b, A_w, A_b, pre_x, hh_b,
                                      gpart, h_cur, c_cur, ctxb, Hall, alphas,
                                      s, (s > 0) ? 1 : 0, 1);
        k_gates<<<dim3(32, 16), 256, 0, stream>>>(ctxb, h_cur, ih_w, hh_w, gpart);
    }
    // final pointwise (produces Hall[29])
    k_att<<<64, 256, 0, stream>>>(features, u_hs, W_w, W_b, A_w, A_b, pre_x, hh_b,
                                  gpart, h_cur, c_cur, ctxb, Hall, alphas,
                                  TT, 1, 0);

    // batched output projection: preds[b,t,:] = Hall[t*64+b] @ fcn_w^T + fcn_b
    gemm_nt<<<dim3(157, 30), 256, 0, stream>>>(Hall, DEC, fcn_w, DEC, fcn_b, out, VOC,
                                               TT * B, VOC, DEC, 1);
}

// Round 2
// 3580.311 us; speedup vs baseline: 1.9333x; 1.9333x over previous
//
#include <hip/hip_runtime.h>
#include <math.h>

// Problem constants
#define B 64
#define NN 49
#define ENC 2048
#define DEC 512
#define ATT 512
#define EMB 300
#define VOC 10000
#define TT 30

__device__ __forceinline__ float fast_tanh(float x) {
    float e = __expf(2.f * x);
    return 1.f - 2.f / (e + 1.f);
}
__device__ __forceinline__ float sigmoidf(float x) {
    return 1.f / (1.f + __expf(-x));
}

// ---------------------------------------------------------------------------
// Generic f32 NT GEMM: C[M,N] = A[M,K] @ B[N,K]^T (+ bias[N])
// mode 0: C row-major ldc. mode 1: preds scatter C[b*T*V + t*V + v], r=t*64+b
// ---------------------------------------------------------------------------
__global__ __launch_bounds__(256) void gemm_nt(
    const float* __restrict__ A, int lda,
    const float* __restrict__ Bm, int ldb,
    const float* __restrict__ bias,
    float* __restrict__ C, int ldc,
    int M, int N, int K, int mode)
{
    const int tid = threadIdx.x;
    const int tx = tid & 15, ty = tid >> 4;
    const int m0 = blockIdx.y * 64, n0 = blockIdx.x * 64;
    __shared__ float As[16][64];
    __shared__ float Bs[16][64];
    float acc[4][4] = {};
    const int lrow = tid >> 2;
    const int lk = (tid & 3) * 4;
    const int nK = (K + 15) >> 4;
    for (int c = 0; c < nK; ++c) {
        const int kk = c * 16 + lk;
        {
            float4 v = {0.f, 0.f, 0.f, 0.f};
            const float* p = A + (size_t)(m0 + lrow) * lda + kk;
            if (kk + 3 < K) v = *(const float4*)p;
            else {
                if (kk + 0 < K) v.x = p[0];
                if (kk + 1 < K) v.y = p[1];
                if (kk + 2 < K) v.z = p[2];
                if (kk + 3 < K) v.w = p[3];
            }
            As[lk + 0][lrow] = v.x; As[lk + 1][lrow] = v.y;
            As[lk + 2][lrow] = v.z; As[lk + 3][lrow] = v.w;
        }
        {
            float4 v = {0.f, 0.f, 0.f, 0.f};
            const int col = n0 + lrow;
            if (col < N) {
                const float* p = Bm + (size_t)col * ldb + kk;
                if (kk + 3 < K) v = *(const float4*)p;
                else {
                    if (kk + 0 < K) v.x = p[0];
                    if (kk + 1 < K) v.y = p[1];
                    if (kk + 2 < K) v.z = p[2];
                    if (kk + 3 < K) v.w = p[3];
                }
            }
            Bs[lk + 0][lrow] = v.x; Bs[lk + 1][lrow] = v.y;
            Bs[lk + 2][lrow] = v.z; Bs[lk + 3][lrow] = v.w;
        }
        __syncthreads();
        #pragma unroll
        for (int k = 0; k < 16; ++k) {
            float4 a = *(const float4*)&As[k][ty * 4];
            float4 b = *(const float4*)&Bs[k][tx * 4];
            acc[0][0] += a.x * b.x; acc[0][1] += a.x * b.y; acc[0][2] += a.x * b.z; acc[0][3] += a.x * b.w;
            acc[1][0] += a.y * b.x; acc[1][1] += a.y * b.y; acc[1][2] += a.y * b.z; acc[1][3] += a.y * b.w;
            acc[2][0] += a.z * b.x; acc[2][1] += a.z * b.y; acc[2][2] += a.z * b.z; acc[2][3] += a.z * b.w;
            acc[3][0] += a.w * b.x; acc[3][1] += a.w * b.y; acc[3][2] += a.w * b.z; acc[3][3] += a.w * b.w;
        }
        __syncthreads();
    }
    #pragma unroll
    for (int i = 0; i < 4; ++i) {
        const int r = m0 + ty * 4 + i;
        if (r >= M) continue;
        #pragma unroll
        for (int j = 0; j < 4; ++j) {
            const int cN = n0 + tx * 4 + j;
            if (cN >= N) continue;
            float val = acc[i][j] + (bias ? bias[cN] : 0.f);
            if (mode == 0) C[(size_t)r * ldc + cN] = val;
            else {
                const int t = r >> 6, bb = r & 63;
                C[(size_t)bb * (TT * VOC) + (size_t)t * VOC + cN] = val;
            }
        }
    }
}

// ---------------------------------------------------------------------------
// mean over N of features -> mean_f [B, ENC]
// ---------------------------------------------------------------------------
__global__ __launch_bounds__(256) void k_mean(const float* __restrict__ f,
                                              float* __restrict__ mean_f)
{
    const int b = blockIdx.x;
    for (int e = threadIdx.x; e < ENC; e += 256) {
        float s = 0.f;
        for (int n = 0; n < NN; ++n) s += f[(size_t)(b * NN + n) * ENC + e];
        mean_f[(size_t)b * ENC + e] = s * (1.f / 49.f);
    }
}

// ---------------------------------------------------------------------------
// embedding gather: embeds[r=t*64+b, :] = emb[captions[b, t], :]
// ---------------------------------------------------------------------------
__global__ __launch_bounds__(256) void k_embed(const int* __restrict__ cap,
                                               const float* __restrict__ emb,
                                               float* __restrict__ embeds)
{
    const int r = blockIdx.x;
    const int t = r >> 6, b = r & 63;
    const int c = cap[b * 31 + t];
    for (int j = threadIdx.x; j < EMB; j += 256)
        embeds[(size_t)r * EMB + j] = emb[(size_t)c * EMB + j];
}

// combined bias: combo[j] = ih_b[j] + hh_b[j]
__global__ void k_bias2(const float* __restrict__ a, const float* __restrict__ b,
                        float* __restrict__ o)
{
    const int j = blockIdx.x * 256 + threadIdx.x;
    if (j < 2048) o[j] = a[j] + b[j];
}

// ---------------------------------------------------------------------------
// K_B: y = h @ [W_w ; hh_w]^T  (M=64, N=2560, K=512), batched weight reuse.
// cols 0..511   -> wah[64][512]  (+ W_b)
// cols 512..2559-> ghh[64][2048] (no bias)
// grid: 40 blocks of 64 cols.
// ---------------------------------------------------------------------------
__global__ __launch_bounds__(256) void k_hw(
    const float* __restrict__ h,
    const float* __restrict__ W_w, const float* __restrict__ W_b,
    const float* __restrict__ hh_w,
    float* __restrict__ wah, float* __restrict__ ghh)
{
    const int tid = threadIdx.x;
    const int tx = tid & 15, ty = tid >> 4;
    const int n0 = blockIdx.x * 64;
    const float* Bp; const float* biasp; float* Cp; int c0, ldc;
    if (n0 < 512) { Bp = W_w + (size_t)n0 * 512; biasp = W_b; Cp = wah; c0 = n0; ldc = 512; }
    else { Bp = hh_w + (size_t)(n0 - 512) * 512; biasp = nullptr; Cp = ghh; c0 = n0 - 512; ldc = 2048; }

    __shared__ float As[16][64];
    __shared__ float Bs[16][64];
    float acc[4][4] = {};
    const int lrow = tid >> 2;
    const int lk = (tid & 3) * 4;
    for (int c = 0; c < 32; ++c) {
        const int kk = c * 16 + lk;
        float4 av = *(const float4*)(h + (size_t)lrow * 512 + kk);
        float4 bv = *(const float4*)(Bp + (size_t)lrow * 512 + kk);
        As[lk + 0][lrow] = av.x; As[lk + 1][lrow] = av.y;
        As[lk + 2][lrow] = av.z; As[lk + 3][lrow] = av.w;
        Bs[lk + 0][lrow] = bv.x; Bs[lk + 1][lrow] = bv.y;
        Bs[lk + 2][lrow] = bv.z; Bs[lk + 3][lrow] = bv.w;
        __syncthreads();
        #pragma unroll
        for (int k = 0; k < 16; ++k) {
            float4 a = *(const float4*)&As[k][ty * 4];
            float4 b = *(const float4*)&Bs[k][tx * 4];
            acc[0][0] += a.x * b.x; acc[0][1] += a.x * b.y; acc[0][2] += a.x * b.z; acc[0][3] += a.x * b.w;
            acc[1][0] += a.y * b.x; acc[1][1] += a.y * b.y; acc[1][2] += a.y * b.z; acc[1][3] += a.y * b.w;
            acc[2][0] += a.z * b.x; acc[2][1] += a.z * b.y; acc[2][2] += a.z * b.z; acc[2][3] += a.z * b.w;
            acc[3][0] += a.w * b.x; acc[3][1] += a.w * b.y; acc[3][2] += a.w * b.z; acc[3][3] += a.w * b.w;
        }
        __syncthreads();
    }
    #pragma unroll
    for (int i = 0; i < 4; ++i) {
        const int r = ty * 4 + i;
        #pragma unroll
        for (int j = 0; j < 4; ++j) {
            const int cc = c0 + tx * 4 + j;
            float val = acc[i][j] + (biasp ? biasp[cc] : 0.f);
            Cp[(size_t)r * ldc + cc] = val;
        }
    }
}

// ---------------------------------------------------------------------------
// K_A: per-b step kernel. Uses wah(h_s), ghh(h_s) precomputed by k_hw.
//  scores -> softmax -> alpha -> gates = pre_x + sum_n alpha*fW + ghh
//  -> pointwise LSTM -> h_{s+1}, c_{s+1}, Hall[s], alphas[s]
// ---------------------------------------------------------------------------
__global__ __launch_bounds__(256) void k_step(
    const float* __restrict__ u_hs,
    const float* __restrict__ A_w, const float* __restrict__ A_b,
    const float* __restrict__ wah,   // [64][512]
    const float* __restrict__ ghh,   // [64][2048]
    const float* __restrict__ pre_x, // [1920][2048] (includes ih_b + hh_b)
    const float* __restrict__ fW,    // [64*49][2048]
    float* __restrict__ h_cur, float* __restrict__ c_cur,
    float* __restrict__ Hall, float* __restrict__ alphas,
    int s)
{
    const int b = blockIdx.x;
    const int tid = threadIdx.x;
    __shared__ float wah_l[512];
    __shared__ float awl[512];
    __shared__ float red[64];
    __shared__ float gl[2048];

    for (int a = tid; a < 512; a += 256) {
        wah_l[a] = wah[b * 512 + a];
        awl[a] = A_w[a];
    }
    __syncthreads();

    // scores[n] = sum_a A_w[a] * tanh(u_hs[b,n,a] + wah[a]) + A_b
    const int lane = tid & 63, wid = tid >> 6;
    for (int n = wid; n < NN; n += 4) {
        const float* up = u_hs + (size_t)(b * NN + n) * 512;
        float acc = 0.f;
        #pragma unroll 2
        for (int a = lane; a < 512; a += 64)
            acc += awl[a] * fast_tanh(up[a] + wah_l[a]);
        #pragma unroll
        for (int m = 32; m; m >>= 1) acc += __shfl_xor(acc, m, 64);
        if (lane == 0) red[n] = acc + A_b[0];
    }
    __syncthreads();

    // softmax over 49 (wave 0)
    if (tid < 64) {
        const float sc = (tid < NN) ? red[tid] : -1e30f;
        float mx = sc;
        #pragma unroll
        for (int m = 32; m; m >>= 1) mx = fmaxf(mx, __shfl_xor(mx, m, 64));
        float e = (tid < NN) ? __expf(sc - mx) : 0.f;
        float sum = e;
        #pragma unroll
        for (int m = 32; m; m >>= 1) sum += __shfl_xor(sum, m, 64);
        const float al = e / sum;
        if (tid < NN) {
            red[tid] = al;
            alphas[(size_t)b * (TT * NN) + (size_t)s * NN + tid] = al;
        }
    }
    __syncthreads();

    // gates[j] = pre_x[s,b,j] + ghh[b,j] + sum_n alpha[n] * fW[b,n,j]
    const float* px = pre_x + (size_t)(s * 64 + b) * 2048;
    const float* gh = ghh + (size_t)b * 2048;
    const float* fb = fW + (size_t)b * NN * 2048;
    for (int j = tid; j < 2048; j += 256) {
        float acc = px[j] + gh[j];
        #pragma unroll 7
        for (int n = 0; n < NN; ++n)
            acc += red[n] * fb[(size_t)n * 2048 + j];
        gl[j] = acc;
    }
    __syncthreads();

    // pointwise LSTM
    for (int d = tid; d < 512; d += 256) {
        const float ig = sigmoidf(gl[d]);
        const float fg = sigmoidf(gl[512 + d]);
        const float gg = fast_tanh(gl[1024 + d]);
        const float og = sigmoidf(gl[1536 + d]);
        const float cv = fg * c_cur[b * 512 + d] + ig * gg;
        const float hv = og * fast_tanh(cv);
        c_cur[b * 512 + d] = cv;
        h_cur[b * 512 + d] = hv;
        Hall[(size_t)(s * 64 + b) * 512 + d] = hv;
    }
}

// ---------------------------------------------------------------------------
extern "C" void kernel_launch(void* const* d_in, const int* in_sizes, int n_in,
                              void* d_out, int out_size, void* d_ws, size_t ws_size,
                              hipStream_t stream)
{
    const float* features = (const float*)d_in[0];
    const int*   captions = (const int*)d_in[1];
    const float* emb      = (const float*)d_in[2];
    const float* U_w      = (const float*)d_in[3];
    const float* U_b      = (const float*)d_in[4];
    const float* W_w      = (const float*)d_in[5];
    const float* W_b      = (const float*)d_in[6];
    const float* A_w      = (const float*)d_in[7];
    const float* A_b      = (const float*)d_in[8];
    const float* iH_w     = (const float*)d_in[9];
    const float* iH_b     = (const float*)d_in[10];
    const float* iC_w     = (const float*)d_in[11];
    const float* iC_b     = (const float*)d_in[12];
    const float* ih_w     = (const float*)d_in[13];
    const float* ih_b     = (const float*)d_in[14];
    const float* hh_w     = (const float*)d_in[15];
    const float* hh_b     = (const float*)d_in[16];
    const float* fcn_w    = (const float*)d_in[17];
    const float* fcn_b    = (const float*)d_in[18];

    float* out    = (float*)d_out;
    float* alphas = out + (size_t)B * TT * VOC;  // 19,200,000

    float* ws     = (float*)d_ws;
    float* fW     = ws;                       // 3136*2048    = 6,422,528
    float* u_hs   = fW + 6422528;             // 3136*512     = 1,605,632
    float* pre_x  = u_hs + 1605632;           // 1920*2048    = 3,932,160
    float* Hall   = pre_x + 3932160;          // 1920*512     = 983,040
    float* mean_f = Hall + 983040;            // 64*2048      = 131,072
    float* h_cur  = mean_f + 131072;          // 32,768
    float* c_cur  = h_cur + 32768;            // 32,768
    float* wah    = c_cur + 32768;            // 64*512       = 32,768
    float* ghh    = wah + 32768;              // 64*2048      = 131,072
    float* embeds = ghh + 131072;             // 1920*300     = 576,000
    float* bias2  = embeds + 576000;          // 2048

    // init hidden state
    k_mean<<<64, 256, 0, stream>>>(features, mean_f);
    gemm_nt<<<dim3(8, 1), 256, 0, stream>>>(mean_f, ENC, iH_w, ENC, iH_b, h_cur, DEC, 64, DEC, ENC, 0);
    gemm_nt<<<dim3(8, 1), 256, 0, stream>>>(mean_f, ENC, iC_w, ENC, iC_b, c_cur, DEC, 64, DEC, ENC, 0);

    // hoisted precomputes
    k_embed<<<1920, 256, 0, stream>>>(captions, emb, embeds);
    k_bias2<<<8, 256, 0, stream>>>(ih_b, hh_b, bias2);
    // u_hs = features @ U_w^T + U_b             [3136, 512]
    gemm_nt<<<dim3(8, 49), 256, 0, stream>>>(features, ENC, U_w, ENC, U_b, u_hs, ATT, B * NN, ATT, ENC, 0);
    // pre_x = embeds @ ih_w[:, :300]^T + (ih_b + hh_b)   [1920, 2048]
    gemm_nt<<<dim3(32, 30), 256, 0, stream>>>(embeds, EMB, ih_w, 2348, bias2, pre_x, 2048, TT * B, 2048, EMB, 0);
    // fW = features @ ih_w[:, 300:2348]^T       [3136, 2048]
    gemm_nt<<<dim3(32, 49), 256, 0, stream>>>(features, ENC, ih_w + 300, 2348, nullptr, fW, 2048, B * NN, 2048, ENC, 0);

    // recurrence: k_hw computes wah/ghh from current h; k_step consumes them.
    k_hw<<<40, 256, 0, stream>>>(h_cur, W_w, W_b, hh_w, wah, ghh);
    for (int s = 0; s < TT; ++s) {
        k_step<<<64, 256, 0, stream>>>(u_hs, A_w, A_b, wah, ghh, pre_x, fW,
                                       h_cur, c_cur, Hall, alphas, s);
        if (s < TT - 1)
            k_hw<<<40, 256, 0, stream>>>(h_cur, W_w, W_b, hh_w, wah, ghh);
    }

    // batched output projection: preds[b,t,:] = Hall[t*64+b] @ fcn_w^T + fcn_b
    gemm_nt<<<dim3(157, 30), 256, 0, stream>>>(Hall, DEC, fcn_w, DEC, fcn_b, out, VOC,
                                               TT * B, VOC, DEC, 1);
}

// Round 3
// 2051.119 us; speedup vs baseline: 3.3746x; 1.7455x over previous
//
#include <hip/hip_runtime.h>
#include <math.h>

// Problem constants
#define B 64
#define NN 49
#define ENC 2048
#define DEC 512
#define ATT 512
#define EMB 300
#define VOC 10000
#define TT 30

typedef __attribute__((ext_vector_type(4))) float f32x4;
typedef __attribute__((ext_vector_type(4))) short s16x4;
typedef __attribute__((ext_vector_type(8))) short s16x8;

__device__ __forceinline__ float fast_tanh(float x) {
    float e = __expf(2.f * x);
    return 1.f - 2.f / (e + 1.f);
}
__device__ __forceinline__ float sigmoidf(float x) {
    return 1.f / (1.f + __expf(-x));
}

// round-to-nearest-even f32 -> bf16 bits
__device__ __forceinline__ unsigned short f2bf(float x) {
    unsigned u = __float_as_uint(x);
    unsigned r = u + 0x7FFFu + ((u >> 16) & 1u);
    return (unsigned short)(r >> 16);
}
__device__ __forceinline__ void split_bf16(float x, short& hi, short& lo) {
    unsigned short h = f2bf(x);
    float hf = __uint_as_float((unsigned)h << 16);
    hi = (short)h;
    lo = (short)f2bf(x - hf);
}
__device__ __forceinline__ s16x8 ld8(const short* p) {
    s16x4 a = *(const s16x4*)p;
    s16x4 b = *(const s16x4*)(p + 4);
    return __builtin_shufflevector(a, b, 0, 1, 2, 3, 4, 5, 6, 7);
}

// ---------------------------------------------------------------------------
// Split-bf16 MFMA NT GEMM: C[M,N] = A[M,K] @ B[N,K]^T (+bias), ~f32 accuracy
// via (Ah+Al)(Bh+Bl) ~= AhBh + AhBl + AlBh.  128x128 tile, 8 waves, 16x16x32.
// mode 0: C[r*ldc+col]. mode 1: preds scatter (r = t*64+b -> [b][t][col]).
// ---------------------------------------------------------------------------
__global__ __launch_bounds__(512) void mfma_nt(
    const float* __restrict__ A, int lda,
    const float* __restrict__ Bm, int ldb,
    const float* __restrict__ bias,
    float* __restrict__ C, int ldc,
    int M, int N, int K, int mode)
{
    __shared__ short Ah[128][40];
    __shared__ short Al[128][40];
    __shared__ short Bh[128][40];
    __shared__ short Bl[128][40];

    const int tid = threadIdx.x;
    const int m0 = blockIdx.y * 128, n0 = blockIdx.x * 128;
    const int wid = tid >> 6, lane = tid & 63;
    const int wm = wid >> 2, wn = wid & 3;        // waves 2 (M) x 4 (N)
    const int lrow = lane & 15;
    const int lko = (lane >> 4) * 8;              // k-offset within 32

    const int srow = tid >> 2;                    // 0..127 staging row
    const int sk = (tid & 3) * 8;                 // 0,8,16,24

    f32x4 acc[4][2];
    #pragma unroll
    for (int i = 0; i < 4; ++i)
        #pragma unroll
        for (int j = 0; j < 2; ++j)
            acc[i][j] = (f32x4){0.f, 0.f, 0.f, 0.f};

    const int nkt = (K + 31) >> 5;
    for (int kt = 0; kt < nkt; ++kt) {
        const int kb0 = kt * 32 + sk;
        // ---- stage A ----
        {
            const int gr = m0 + srow;
            float v[8];
            if (gr < M && kb0 + 7 < K) {
                const float* p = A + (size_t)gr * lda + kb0;
                float4 x0 = *(const float4*)p;
                float4 x1 = *(const float4*)(p + 4);
                v[0] = x0.x; v[1] = x0.y; v[2] = x0.z; v[3] = x0.w;
                v[4] = x1.x; v[5] = x1.y; v[6] = x1.z; v[7] = x1.w;
            } else {
                #pragma unroll
                for (int j = 0; j < 8; ++j)
                    v[j] = (gr < M && kb0 + j < K) ? A[(size_t)gr * lda + kb0 + j] : 0.f;
            }
            s16x4 h0, h1, l0, l1;
            #pragma unroll
            for (int j = 0; j < 4; ++j) { short h, l; split_bf16(v[j], h, l); h0[j] = h; l0[j] = l; }
            #pragma unroll
            for (int j = 0; j < 4; ++j) { short h, l; split_bf16(v[4 + j], h, l); h1[j] = h; l1[j] = l; }
            *(s16x4*)&Ah[srow][sk] = h0; *(s16x4*)&Ah[srow][sk + 4] = h1;
            *(s16x4*)&Al[srow][sk] = l0; *(s16x4*)&Al[srow][sk + 4] = l1;
        }
        // ---- stage B ----
        {
            const int gc = n0 + srow;
            float v[8];
            if (gc < N && kb0 + 7 < K) {
                const float* p = Bm + (size_t)gc * ldb + kb0;
                float4 x0 = *(const float4*)p;
                float4 x1 = *(const float4*)(p + 4);
                v[0] = x0.x; v[1] = x0.y; v[2] = x0.z; v[3] = x0.w;
                v[4] = x1.x; v[5] = x1.y; v[6] = x1.z; v[7] = x1.w;
            } else {
                #pragma unroll
                for (int j = 0; j < 8; ++j)
                    v[j] = (gc < N && kb0 + j < K) ? Bm[(size_t)gc * ldb + kb0 + j] : 0.f;
            }
            s16x4 h0, h1, l0, l1;
            #pragma unroll
            for (int j = 0; j < 4; ++j) { short h, l; split_bf16(v[j], h, l); h0[j] = h; l0[j] = l; }
            #pragma unroll
            for (int j = 0; j < 4; ++j) { short h, l; split_bf16(v[4 + j], h, l); h1[j] = h; l1[j] = l; }
            *(s16x4*)&Bh[srow][sk] = h0; *(s16x4*)&Bh[srow][sk + 4] = h1;
            *(s16x4*)&Bl[srow][sk] = l0; *(s16x4*)&Bl[srow][sk + 4] = l1;
        }
        __syncthreads();

        s16x8 bh[2], bl[2];
        #pragma unroll
        for (int nr = 0; nr < 2; ++nr) {
            const int col = wn * 32 + nr * 16 + lrow;
            bh[nr] = ld8(&Bh[col][lko]);
            bl[nr] = ld8(&Bl[col][lko]);
        }
        #pragma unroll
        for (int mr = 0; mr < 4; ++mr) {
            const int row = wm * 64 + mr * 16 + lrow;
            s16x8 ah = ld8(&Ah[row][lko]);
            s16x8 al = ld8(&Al[row][lko]);
            #pragma unroll
            for (int nr = 0; nr < 2; ++nr) {
                acc[mr][nr] = __builtin_amdgcn_mfma_f32_16x16x32_bf16(ah, bh[nr], acc[mr][nr], 0, 0, 0);
                acc[mr][nr] = __builtin_amdgcn_mfma_f32_16x16x32_bf16(ah, bl[nr], acc[mr][nr], 0, 0, 0);
                acc[mr][nr] = __builtin_amdgcn_mfma_f32_16x16x32_bf16(al, bh[nr], acc[mr][nr], 0, 0, 0);
            }
        }
        __syncthreads();
    }

    // epilogue: D layout col=lane&15, row=(lane>>4)*4+reg
    #pragma unroll
    for (int mr = 0; mr < 4; ++mr) {
        #pragma unroll
        for (int nr = 0; nr < 2; ++nr) {
            #pragma unroll
            for (int r = 0; r < 4; ++r) {
                const int row = m0 + wm * 64 + mr * 16 + (lane >> 4) * 4 + r;
                const int col = n0 + wn * 32 + nr * 16 + (lane & 15);
                if (row < M && col < N) {
                    float val = acc[mr][nr][r] + (bias ? bias[col] : 0.f);
                    if (mode == 0) C[(size_t)row * ldc + col] = val;
                    else {
                        const int t = row >> 6, bb = row & 63;
                        C[(size_t)bb * (TT * VOC) + (size_t)t * VOC + col] = val;
                    }
                }
            }
        }
    }
}

// ---------------------------------------------------------------------------
// small f32 NT GEMM (64-tiles) for the two init projections
// ---------------------------------------------------------------------------
__global__ __launch_bounds__(256) void gemm_nt(
    const float* __restrict__ A, int lda,
    const float* __restrict__ Bm, int ldb,
    const float* __restrict__ bias,
    float* __restrict__ C, int ldc,
    int M, int N, int K)
{
    const int tid = threadIdx.x;
    const int tx = tid & 15, ty = tid >> 4;
    const int m0 = blockIdx.y * 64, n0 = blockIdx.x * 64;
    __shared__ float As[16][64];
    __shared__ float Bs[16][64];
    float acc[4][4] = {};
    const int lrow = tid >> 2;
    const int lk = (tid & 3) * 4;
    const int nK = (K + 15) >> 4;
    for (int c = 0; c < nK; ++c) {
        const int kk = c * 16 + lk;
        {
            float4 v = {0.f, 0.f, 0.f, 0.f};
            const float* p = A + (size_t)(m0 + lrow) * lda + kk;
            if (kk + 3 < K) v = *(const float4*)p;
            As[lk + 0][lrow] = v.x; As[lk + 1][lrow] = v.y;
            As[lk + 2][lrow] = v.z; As[lk + 3][lrow] = v.w;
        }
        {
            float4 v = {0.f, 0.f, 0.f, 0.f};
            const int col = n0 + lrow;
            if (col < N && kk + 3 < K) v = *(const float4*)(Bm + (size_t)col * ldb + kk);
            Bs[lk + 0][lrow] = v.x; Bs[lk + 1][lrow] = v.y;
            Bs[lk + 2][lrow] = v.z; Bs[lk + 3][lrow] = v.w;
        }
        __syncthreads();
        #pragma unroll
        for (int k = 0; k < 16; ++k) {
            float4 a = *(const float4*)&As[k][ty * 4];
            float4 b = *(const float4*)&Bs[k][tx * 4];
            acc[0][0] += a.x * b.x; acc[0][1] += a.x * b.y; acc[0][2] += a.x * b.z; acc[0][3] += a.x * b.w;
            acc[1][0] += a.y * b.x; acc[1][1] += a.y * b.y; acc[1][2] += a.y * b.z; acc[1][3] += a.y * b.w;
            acc[2][0] += a.z * b.x; acc[2][1] += a.z * b.y; acc[2][2] += a.z * b.z; acc[2][3] += a.z * b.w;
            acc[3][0] += a.w * b.x; acc[3][1] += a.w * b.y; acc[3][2] += a.w * b.z; acc[3][3] += a.w * b.w;
        }
        __syncthreads();
    }
    #pragma unroll
    for (int i = 0; i < 4; ++i) {
        const int r = m0 + ty * 4 + i;
        if (r >= M) continue;
        #pragma unroll
        for (int j = 0; j < 4; ++j) {
            const int cN = n0 + tx * 4 + j;
            if (cN >= N) continue;
            C[(size_t)r * ldc + cN] = acc[i][j] + (bias ? bias[cN] : 0.f);
        }
    }
}

__global__ __launch_bounds__(256) void k_mean(const float* __restrict__ f,
                                              float* __restrict__ mean_f)
{
    const int b = blockIdx.x;
    for (int e = threadIdx.x; e < ENC; e += 256) {
        float s = 0.f;
        for (int n = 0; n < NN; ++n) s += f[(size_t)(b * NN + n) * ENC + e];
        mean_f[(size_t)b * ENC + e] = s * (1.f / 49.f);
    }
}

__global__ __launch_bounds__(256) void k_embed(const int* __restrict__ cap,
                                               const float* __restrict__ emb,
                                               float* __restrict__ embeds)
{
    const int r = blockIdx.x;
    const int t = r >> 6, b = r & 63;
    const int c = cap[b * 31 + t];
    for (int j = threadIdx.x; j < EMB; j += 256)
        embeds[(size_t)r * EMB + j] = emb[(size_t)c * EMB + j];
}

__global__ void k_bias2(const float* __restrict__ a, const float* __restrict__ b,
                        float* __restrict__ o)
{
    const int j = blockIdx.x * 256 + threadIdx.x;
    if (j < 2048) o[j] = a[j] + b[j];
}

// ---------------------------------------------------------------------------
// wah/ghh split-K GEMM: grid (40, 2). y = h @ [W_w ; hh_w]^T over K-half.
// cols 0..511 -> wahp[ks][64][512] (+W_b at ks 0); else ghhp[ks][64][2048].
// ---------------------------------------------------------------------------
__global__ __launch_bounds__(256) void k_hw2(
    const float* __restrict__ h,
    const float* __restrict__ W_w, const float* __restrict__ W_b,
    const float* __restrict__ hh_w,
    float* __restrict__ wahp, float* __restrict__ ghhp)
{
    const int tid = threadIdx.x;
    const int tx = tid & 15, ty = tid >> 4;
    const int n0 = blockIdx.x * 64;
    const int ks = blockIdx.y;
    const float* Bp; const float* biasp; float* Cp; int c0, ldc;
    if (n0 < 512) { Bp = W_w + (size_t)n0 * 512; biasp = (ks == 0) ? W_b : nullptr; Cp = wahp + (size_t)ks * 64 * 512; c0 = n0; ldc = 512; }
    else { Bp = hh_w + (size_t)(n0 - 512) * 512; biasp = nullptr; Cp = ghhp + (size_t)ks * 64 * 2048; c0 = n0 - 512; ldc = 2048; }

    __shared__ float As[16][64];
    __shared__ float Bs[16][64];
    float acc[4][4] = {};
    const int lrow = tid >> 2;
    const int lk = (tid & 3) * 4;
    for (int c = 0; c < 16; ++c) {
        const int kk = ks * 256 + c * 16 + lk;
        float4 av = *(const float4*)(h + (size_t)lrow * 512 + kk);
        float4 bv = *(const float4*)(Bp + (size_t)lrow * 512 + kk);
        As[lk + 0][lrow] = av.x; As[lk + 1][lrow] = av.y;
        As[lk + 2][lrow] = av.z; As[lk + 3][lrow] = av.w;
        Bs[lk + 0][lrow] = bv.x; Bs[lk + 1][lrow] = bv.y;
        Bs[lk + 2][lrow] = bv.z; Bs[lk + 3][lrow] = bv.w;
        __syncthreads();
        #pragma unroll
        for (int k = 0; k < 16; ++k) {
            float4 a = *(const float4*)&As[k][ty * 4];
            float4 b = *(const float4*)&Bs[k][tx * 4];
            acc[0][0] += a.x * b.x; acc[0][1] += a.x * b.y; acc[0][2] += a.x * b.z; acc[0][3] += a.x * b.w;
            acc[1][0] += a.y * b.x; acc[1][1] += a.y * b.y; acc[1][2] += a.y * b.z; acc[1][3] += a.y * b.w;
            acc[2][0] += a.z * b.x; acc[2][1] += a.z * b.y; acc[2][2] += a.z * b.z; acc[2][3] += a.z * b.w;
            acc[3][0] += a.w * b.x; acc[3][1] += a.w * b.y; acc[3][2] += a.w * b.z; acc[3][3] += a.w * b.w;
        }
        __syncthreads();
    }
    #pragma unroll
    for (int i = 0; i < 4; ++i) {
        const int r = ty * 4 + i;
        #pragma unroll
        for (int j = 0; j < 4; ++j) {
            const int cc = c0 + tx * 4 + j;
            Cp[(size_t)r * ldc + cc] = acc[i][j] + (biasp ? biasp[cc] : 0.f);
        }
    }
}

// ---------------------------------------------------------------------------
// scores + softmax per b (grid 64)
// ---------------------------------------------------------------------------
__global__ __launch_bounds__(256) void k_score(
    const float* __restrict__ u_hs,
    const float* __restrict__ A_w, const float* __restrict__ A_b,
    const float* __restrict__ wahp,
    float* __restrict__ alphas, float* __restrict__ abuf,
    int s)
{
    const int b = blockIdx.x;
    const int tid = threadIdx.x;
    __shared__ float wah_l[512];
    __shared__ float awl[512];
    __shared__ float red[64];

    for (int a = tid; a < 512; a += 256) {
        wah_l[a] = wahp[b * 512 + a] + wahp[32768 + b * 512 + a];
        awl[a] = A_w[a];
    }
    __syncthreads();

    const int lane = tid & 63, wid = tid >> 6;
    for (int n = wid; n < NN; n += 4) {
        const float* up = u_hs + (size_t)(b * NN + n) * 512;
        float acc = 0.f;
        #pragma unroll 2
        for (int a = lane; a < 512; a += 64)
            acc += awl[a] * fast_tanh(up[a] + wah_l[a]);
        #pragma unroll
        for (int m = 32; m; m >>= 1) acc += __shfl_xor(acc, m, 64);
        if (lane == 0) red[n] = acc + A_b[0];
    }
    __syncthreads();

    if (tid < 64) {
        const float sc = (tid < NN) ? red[tid] : -1e30f;
        float mx = sc;
        #pragma unroll
        for (int m = 32; m; m >>= 1) mx = fmaxf(mx, __shfl_xor(mx, m, 64));
        float e = (tid < NN) ? __expf(sc - mx) : 0.f;
        float sum = e;
        #pragma unroll
        for (int m = 32; m; m >>= 1) sum += __shfl_xor(sum, m, 64);
        const float al = e / sum;
        if (tid < NN) {
            abuf[b * 64 + tid] = al;
            alphas[(size_t)b * (TT * NN) + (size_t)s * NN + tid] = al;
        }
    }
}

// ---------------------------------------------------------------------------
// gates + LSTM pointwise: grid (64 b, 4 d-chunks), 256 threads.
// threads 0-127 own gate quads i,f; 128-255 own g,o (via LDS handoff).
// ---------------------------------------------------------------------------
__global__ __launch_bounds__(256) void k_gate(
    const float* __restrict__ pre_x,
    const float* __restrict__ ghhp,
    const float* __restrict__ fW,
    const float* __restrict__ abuf,
    float* __restrict__ h_cur, float* __restrict__ c_cur,
    float* __restrict__ Hall, int s)
{
    const int b = blockIdx.x;
    const int q = blockIdx.y;
    const int tid = threadIdx.x;
    const int half = tid >> 7;
    const int d = tid & 127;
    __shared__ float al[64];
    __shared__ float ghi[2][128];

    if (tid < 64) al[tid] = (tid < NN) ? abuf[b * 64 + tid] : 0.f;
    __syncthreads();

    const int j0 = (half * 2) * 512 + q * 128 + d;
    const int j1 = (half * 2 + 1) * 512 + q * 128 + d;
    const float* px = pre_x + (size_t)(s * 64 + b) * 2048;
    const float* g0p = ghhp + (size_t)b * 2048;
    const float* g1p = ghhp + 131072 + (size_t)b * 2048;
    float a0 = px[j0] + g0p[j0] + g1p[j0];
    float a1 = px[j1] + g0p[j1] + g1p[j1];
    const float* fb = fW + (size_t)b * NN * 2048;
    #pragma unroll 7
    for (int n = 0; n < NN; ++n) {
        const float w = al[n];
        a0 += w * fb[(size_t)n * 2048 + j0];
        a1 += w * fb[(size_t)n * 2048 + j1];
    }
    if (half) { ghi[0][d] = a0; ghi[1][d] = a1; }
    __syncthreads();
    if (!half) {
        const float ig = sigmoidf(a0);
        const float fg = sigmoidf(a1);
        const float gg = fast_tanh(ghi[0][d]);
        const float og = sigmoidf(ghi[1][d]);
        const int dd = q * 128 + d;
        const float cv = fg * c_cur[b * 512 + dd] + ig * gg;
        const float hv = og * fast_tanh(cv);
        c_cur[b * 512 + dd] = cv;
        h_cur[b * 512 + dd] = hv;
        Hall[(size_t)(s * 64 + b) * 512 + dd] = hv;
    }
}

// ---------------------------------------------------------------------------
extern "C" void kernel_launch(void* const* d_in, const int* in_sizes, int n_in,
                              void* d_out, int out_size, void* d_ws, size_t ws_size,
                              hipStream_t stream)
{
    const float* features = (const float*)d_in[0];
    const int*   captions = (const int*)d_in[1];
    const float* emb      = (const float*)d_in[2];
    const float* U_w      = (const float*)d_in[3];
    const float* U_b      = (const float*)d_in[4];
    const float* W_w      = (const float*)d_in[5];
    const float* W_b      = (const float*)d_in[6];
    const float* A_w      = (const float*)d_in[7];
    const float* A_b      = (const float*)d_in[8];
    const float* iH_w     = (const float*)d_in[9];
    const float* iH_b     = (const float*)d_in[10];
    const float* iC_w     = (const float*)d_in[11];
    const float* iC_b     = (const float*)d_in[12];
    const float* ih_w     = (const float*)d_in[13];
    const float* ih_b     = (const float*)d_in[14];
    const float* hh_w     = (const float*)d_in[15];
    const float* hh_b     = (const float*)d_in[16];
    const float* fcn_w    = (const float*)d_in[17];
    const float* fcn_b    = (const float*)d_in[18];

    float* out    = (float*)d_out;
    float* alphas = out + (size_t)B * TT * VOC;

    float* ws     = (float*)d_ws;
    float* fW     = ws;                       // 3136*2048 = 6,422,528
    float* u_hs   = fW + 6422528;             // 3136*512  = 1,605,632
    float* pre_x  = u_hs + 1605632;           // 1920*2048 = 3,932,160
    float* Hall   = pre_x + 3932160;          // 1920*512  = 983,040
    float* mean_f = Hall + 983040;            // 131,072
    float* h_cur  = mean_f + 131072;          // 32,768
    float* c_cur  = h_cur + 32768;            // 32,768
    float* wahp   = c_cur + 32768;            // 2*64*512  = 65,536
    float* ghhp   = wahp + 65536;             // 2*64*2048 = 262,144
    float* abuf   = ghhp + 262144;            // 64*64     = 4,096
    float* embeds = abuf + 4096;              // 1920*300  = 576,000
    float* bias2  = embeds + 576000;          // 2,048

    // init hidden state
    k_mean<<<64, 256, 0, stream>>>(features, mean_f);
    gemm_nt<<<dim3(8, 1), 256, 0, stream>>>(mean_f, ENC, iH_w, ENC, iH_b, h_cur, DEC, 64, DEC, ENC);
    gemm_nt<<<dim3(8, 1), 256, 0, stream>>>(mean_f, ENC, iC_w, ENC, iC_b, c_cur, DEC, 64, DEC, ENC);

    // hoisted precomputes
    k_embed<<<1920, 256, 0, stream>>>(captions, emb, embeds);
    k_bias2<<<8, 256, 0, stream>>>(ih_b, hh_b, bias2);
    // u_hs = features @ U_w^T + U_b                 [3136, 512]
    mfma_nt<<<dim3(4, 25), 512, 0, stream>>>(features, ENC, U_w, ENC, U_b, u_hs, ATT, B * NN, ATT, ENC, 0);
    // pre_x = embeds @ ih_w[:, :300]^T + (ih_b+hh_b) [1920, 2048]
    mfma_nt<<<dim3(16, 15), 512, 0, stream>>>(embeds, EMB, ih_w, 2348, bias2, pre_x, 2048, TT * B, 2048, EMB, 0);
    // fW = features @ ih_w[:, 300:2348]^T            [3136, 2048]
    mfma_nt<<<dim3(16, 25), 512, 0, stream>>>(features, ENC, ih_w + 300, 2348, nullptr, fW, 2048, B * NN, 2048, ENC, 0);

    // recurrence
    k_hw2<<<dim3(40, 2), 256, 0, stream>>>(h_cur, W_w, W_b, hh_w, wahp, ghhp);
    for (int s = 0; s < TT; ++s) {
        k_score<<<64, 256, 0, stream>>>(u_hs, A_w, A_b, wahp, alphas, abuf, s);
        k_gate<<<dim3(64, 4), 256, 0, stream>>>(pre_x, ghhp, fW, abuf, h_cur, c_cur, Hall, s);
        if (s < TT - 1)
            k_hw2<<<dim3(40, 2), 256, 0, stream>>>(h_cur, W_w, W_b, hh_w, wahp, ghhp);
    }

    // batched output projection
    mfma_nt<<<dim3(79, 15), 512, 0, stream>>>(Hall, DEC, fcn_w, DEC, fcn_b, out, VOC,
                                              TT * B, VOC, DEC, 1);
}

// Round 4
// 1298.393 us; speedup vs baseline: 5.3310x; 1.5797x over previous
//
#include <hip/hip_runtime.h>
#include <math.h>

// Problem constants
#define B 64
#define NN 49
#define ENC 2048
#define DEC 512
#define ATT 512
#define EMB 300
#define VOC 10000
#define TT 30

typedef __attribute__((ext_vector_type(4))) float f32x4;
typedef __attribute__((ext_vector_type(4))) short s16x4;
typedef __attribute__((ext_vector_type(8))) short s16x8;

__device__ __forceinline__ float fast_tanh(float x) {
    float e = __expf(2.f * x);
    return 1.f - 2.f / (e + 1.f);
}
__device__ __forceinline__ float sigmoidf(float x) {
    return 1.f / (1.f + __expf(-x));
}

// round-to-nearest-even f32 -> bf16 bits
__device__ __forceinline__ unsigned short f2bf(float x) {
    unsigned u = __float_as_uint(x);
    unsigned r = u + 0x7FFFu + ((u >> 16) & 1u);
    return (unsigned short)(r >> 16);
}
__device__ __forceinline__ void split_bf16(float x, short& hi, short& lo) {
    unsigned short h = f2bf(x);
    float hf = __uint_as_float((unsigned)h << 16);
    hi = (short)h;
    lo = (short)f2bf(x - hf);
}
__device__ __forceinline__ s16x8 ld8(const short* p) {
    s16x4 a = *(const s16x4*)p;
    s16x4 b = *(const s16x4*)(p + 4);
    return __builtin_shufflevector(a, b, 0, 1, 2, 3, 4, 5, 6, 7);
}

// ---------------------------------------------------------------------------
// Split-bf16 MFMA NT GEMM: C[M,N] = A[M,K] @ B[N,K]^T (+bias), ~f32 accuracy
// via (Ah+Al)(Bh+Bl) ~= AhBh + AhBl + AlBh.  128x128 tile, 8 waves, 16x16x32.
// mode 0: C[r*ldc+col]. mode 1: preds scatter (r = t*64+b -> [b][t][col]).
// ---------------------------------------------------------------------------
__global__ __launch_bounds__(512) void mfma_nt(
    const float* __restrict__ A, int lda,
    const float* __restrict__ Bm, int ldb,
    const float* __restrict__ bias,
    float* __restrict__ C, int ldc,
    int M, int N, int K, int mode)
{
    __shared__ short Ah[128][40];
    __shared__ short Al[128][40];
    __shared__ short Bh[128][40];
    __shared__ short Bl[128][40];

    const int tid = threadIdx.x;
    const int m0 = blockIdx.y * 128, n0 = blockIdx.x * 128;
    const int wid = tid >> 6, lane = tid & 63;
    const int wm = wid >> 2, wn = wid & 3;        // waves 2 (M) x 4 (N)
    const int lrow = lane & 15;
    const int lko = (lane >> 4) * 8;              // k-offset within 32

    const int srow = tid >> 2;                    // 0..127 staging row
    const int sk = (tid & 3) * 8;                 // 0,8,16,24

    f32x4 acc[4][2];
    #pragma unroll
    for (int i = 0; i < 4; ++i)
        #pragma unroll
        for (int j = 0; j < 2; ++j)
            acc[i][j] = (f32x4){0.f, 0.f, 0.f, 0.f};

    const int nkt = (K + 31) >> 5;
    for (int kt = 0; kt < nkt; ++kt) {
        const int kb0 = kt * 32 + sk;
        // ---- stage A ----
        {
            const int gr = m0 + srow;
            float v[8];
            if (gr < M && kb0 + 7 < K) {
                const float* p = A + (size_t)gr * lda + kb0;
                float4 x0 = *(const float4*)p;
                float4 x1 = *(const float4*)(p + 4);
                v[0] = x0.x; v[1] = x0.y; v[2] = x0.z; v[3] = x0.w;
                v[4] = x1.x; v[5] = x1.y; v[6] = x1.z; v[7] = x1.w;
            } else {
                #pragma unroll
                for (int j = 0; j < 8; ++j)
                    v[j] = (gr < M && kb0 + j < K) ? A[(size_t)gr * lda + kb0 + j] : 0.f;
            }
            s16x4 h0, h1, l0, l1;
            #pragma unroll
            for (int j = 0; j < 4; ++j) { short h, l; split_bf16(v[j], h, l); h0[j] = h; l0[j] = l; }
            #pragma unroll
            for (int j = 0; j < 4; ++j) { short h, l; split_bf16(v[4 + j], h, l); h1[j] = h; l1[j] = l; }
            *(s16x4*)&Ah[srow][sk] = h0; *(s16x4*)&Ah[srow][sk + 4] = h1;
            *(s16x4*)&Al[srow][sk] = l0; *(s16x4*)&Al[srow][sk + 4] = l1;
        }
        // ---- stage B ----
        {
            const int gc = n0 + srow;
            float v[8];
            if (gc < N && kb0 + 7 < K) {
                const float* p = Bm + (size_t)gc * ldb + kb0;
                float4 x0 = *(const float4*)p;
                float4 x1 = *(const float4*)(p + 4);
                v[0] = x0.x; v[1] = x0.y; v[2] = x0.z; v[3] = x0.w;
                v[4] = x1.x; v[5] = x1.y; v[6] = x1.z; v[7] = x1.w;
            } else {
                #pragma unroll
                for (int j = 0; j < 8; ++j)
                    v[j] = (gc < N && kb0 + j < K) ? Bm[(size_t)gc * ldb + kb0 + j] : 0.f;
            }
            s16x4 h0, h1, l0, l1;
            #pragma unroll
            for (int j = 0; j < 4; ++j) { short h, l; split_bf16(v[j], h, l); h0[j] = h; l0[j] = l; }
            #pragma unroll
            for (int j = 0; j < 4; ++j) { short h, l; split_bf16(v[4 + j], h, l); h1[j] = h; l1[j] = l; }
            *(s16x4*)&Bh[srow][sk] = h0; *(s16x4*)&Bh[srow][sk + 4] = h1;
            *(s16x4*)&Bl[srow][sk] = l0; *(s16x4*)&Bl[srow][sk + 4] = l1;
        }
        __syncthreads();

        s16x8 bh[2], bl[2];
        #pragma unroll
        for (int nr = 0; nr < 2; ++nr) {
            const int col = wn * 32 + nr * 16 + lrow;
            bh[nr] = ld8(&Bh[col][lko]);
            bl[nr] = ld8(&Bl[col][lko]);
        }
        #pragma unroll
        for (int mr = 0; mr < 4; ++mr) {
            const int row = wm * 64 + mr * 16 + lrow;
            s16x8 ah = ld8(&Ah[row][lko]);
            s16x8 al = ld8(&Al[row][lko]);
            #pragma unroll
            for (int nr = 0; nr < 2; ++nr) {
                acc[mr][nr] = __builtin_amdgcn_mfma_f32_16x16x32_bf16(ah, bh[nr], acc[mr][nr], 0, 0, 0);
                acc[mr][nr] = __builtin_amdgcn_mfma_f32_16x16x32_bf16(ah, bl[nr], acc[mr][nr], 0, 0, 0);
                acc[mr][nr] = __builtin_amdgcn_mfma_f32_16x16x32_bf16(al, bh[nr], acc[mr][nr], 0, 0, 0);
            }
        }
        __syncthreads();
    }

    // epilogue: D layout col=lane&15, row=(lane>>4)*4+reg
    #pragma unroll
    for (int mr = 0; mr < 4; ++mr) {
        #pragma unroll
        for (int nr = 0; nr < 2; ++nr) {
            #pragma unroll
            for (int r = 0; r < 4; ++r) {
                const int row = m0 + wm * 64 + mr * 16 + (lane >> 4) * 4 + r;
                const int col = n0 + wn * 32 + nr * 16 + (lane & 15);
                if (row < M && col < N) {
                    float val = acc[mr][nr][r] + (bias ? bias[col] : 0.f);
                    if (mode == 0) C[(size_t)row * ldc + col] = val;
                    else {
                        const int t = row >> 6, bb = row & 63;
                        C[(size_t)bb * (TT * VOC) + (size_t)t * VOC + col] = val;
                    }
                }
            }
        }
    }
}

__global__ __launch_bounds__(256) void k_mean(const float* __restrict__ f,
                                              float* __restrict__ mean_f)
{
    const int b = blockIdx.x;
    for (int e = threadIdx.x; e < ENC; e += 256) {
        float s = 0.f;
        for (int n = 0; n < NN; ++n) s += f[(size_t)(b * NN + n) * ENC + e];
        mean_f[(size_t)b * ENC + e] = s * (1.f / 49.f);
    }
}

// ---------------------------------------------------------------------------
// init h0/c0, split-K: grid (16 colblocks of 64 in [0,1024), 16 kslices of 128)
// cols 0..511 -> iH rows, 512..1023 -> iC rows. pbuf[ks][64][1024].
// ---------------------------------------------------------------------------
__global__ __launch_bounds__(256) void k_init_partial(
    const float* __restrict__ mean_f,
    const float* __restrict__ iH_w, const float* __restrict__ iC_w,
    float* __restrict__ pbuf)
{
    const int tid = threadIdx.x;
    const int tx = tid & 15, ty = tid >> 4;
    const int n0 = blockIdx.x * 64;
    const int ks = blockIdx.y;
    __shared__ float As[16][64];
    __shared__ float Bs[16][64];
    float acc[4][4] = {};
    const int lrow = tid >> 2;
    const int lk = (tid & 3) * 4;
    for (int c = 0; c < 8; ++c) {
        const int kk = ks * 128 + c * 16 + lk;
        float4 av = *(const float4*)(mean_f + (size_t)lrow * 2048 + kk);
        const int col = n0 + lrow;
        const float* wp = (col < 512) ? (iH_w + (size_t)col * 2048)
                                      : (iC_w + (size_t)(col - 512) * 2048);
        float4 bv = *(const float4*)(wp + kk);
        As[lk + 0][lrow] = av.x; As[lk + 1][lrow] = av.y;
        As[lk + 2][lrow] = av.z; As[lk + 3][lrow] = av.w;
        Bs[lk + 0][lrow] = bv.x; Bs[lk + 1][lrow] = bv.y;
        Bs[lk + 2][lrow] = bv.z; Bs[lk + 3][lrow] = bv.w;
        __syncthreads();
        #pragma unroll
        for (int k = 0; k < 16; ++k) {
            float4 a = *(const float4*)&As[k][ty * 4];
            float4 b = *(const float4*)&Bs[k][tx * 4];
            acc[0][0] += a.x * b.x; acc[0][1] += a.x * b.y; acc[0][2] += a.x * b.z; acc[0][3] += a.x * b.w;
            acc[1][0] += a.y * b.x; acc[1][1] += a.y * b.y; acc[1][2] += a.y * b.z; acc[1][3] += a.y * b.w;
            acc[2][0] += a.z * b.x; acc[2][1] += a.z * b.y; acc[2][2] += a.z * b.z; acc[2][3] += a.z * b.w;
            acc[3][0] += a.w * b.x; acc[3][1] += a.w * b.y; acc[3][2] += a.w * b.z; acc[3][3] += a.w * b.w;
        }
        __syncthreads();
    }
    #pragma unroll
    for (int i = 0; i < 4; ++i) {
        const int r = ty * 4 + i;
        #pragma unroll
        for (int j = 0; j < 4; ++j)
            pbuf[(size_t)(ks * 64 + r) * 1024 + n0 + tx * 4 + j] = acc[i][j];
    }
}

__global__ __launch_bounds__(256) void k_init_reduce(
    const float* __restrict__ pbuf,
    const float* __restrict__ iH_b, const float* __restrict__ iC_b,
    float* __restrict__ h_cur, float* __restrict__ c_cur)
{
    const int idx = blockIdx.x * 256 + threadIdx.x;   // 0..65535
    const int r = idx >> 10, c = idx & 1023;
    float s = 0.f;
    #pragma unroll
    for (int ks = 0; ks < 16; ++ks) s += pbuf[(size_t)(ks * 64 + r) * 1024 + c];
    if (c < 512) h_cur[r * 512 + c] = s + iH_b[c];
    else         c_cur[r * 512 + (c - 512)] = s + iC_b[c - 512];
}

__global__ __launch_bounds__(256) void k_embed(const int* __restrict__ cap,
                                               const float* __restrict__ emb,
                                               float* __restrict__ embeds)
{
    const int r = blockIdx.x;
    const int t = r >> 6, b = r & 63;
    const int c = cap[b * 31 + t];
    for (int j = threadIdx.x; j < EMB; j += 256)
        embeds[(size_t)r * EMB + j] = emb[(size_t)c * EMB + j];
}

__global__ void k_bias2(const float* __restrict__ a, const float* __restrict__ b,
                        float* __restrict__ o)
{
    const int j = blockIdx.x * 256 + threadIdx.x;
    if (j < 2048) o[j] = a[j] + b[j];
}

// ---------------------------------------------------------------------------
// wah/ghh split-K GEMM: grid (40, 2). y = h @ [W_w ; hh_w]^T over K-half.
// ---------------------------------------------------------------------------
__global__ __launch_bounds__(256) void k_hw2(
    const float* __restrict__ h,
    const float* __restrict__ W_w, const float* __restrict__ W_b,
    const float* __restrict__ hh_w,
    float* __restrict__ wahp, float* __restrict__ ghhp)
{
    const int tid = threadIdx.x;
    const int tx = tid & 15, ty = tid >> 4;
    const int n0 = blockIdx.x * 64;
    const int ks = blockIdx.y;
    const float* Bp; const float* biasp; float* Cp; int c0, ldc;
    if (n0 < 512) { Bp = W_w + (size_t)n0 * 512; biasp = (ks == 0) ? W_b : nullptr; Cp = wahp + (size_t)ks * 64 * 512; c0 = n0; ldc = 512; }
    else { Bp = hh_w + (size_t)(n0 - 512) * 512; biasp = nullptr; Cp = ghhp + (size_t)ks * 64 * 2048; c0 = n0 - 512; ldc = 2048; }

    __shared__ float As[16][64];
    __shared__ float Bs[16][64];
    float acc[4][4] = {};
    const int lrow = tid >> 2;
    const int lk = (tid & 3) * 4;
    for (int c = 0; c < 16; ++c) {
        const int kk = ks * 256 + c * 16 + lk;
        float4 av = *(const float4*)(h + (size_t)lrow * 512 + kk);
        float4 bv = *(const float4*)(Bp + (size_t)lrow * 512 + kk);
        As[lk + 0][lrow] = av.x; As[lk + 1][lrow] = av.y;
        As[lk + 2][lrow] = av.z; As[lk + 3][lrow] = av.w;
        Bs[lk + 0][lrow] = bv.x; Bs[lk + 1][lrow] = bv.y;
        Bs[lk + 2][lrow] = bv.z; Bs[lk + 3][lrow] = bv.w;
        __syncthreads();
        #pragma unroll
        for (int k = 0; k < 16; ++k) {
            float4 a = *(const float4*)&As[k][ty * 4];
            float4 b = *(const float4*)&Bs[k][tx * 4];
            acc[0][0] += a.x * b.x; acc[0][1] += a.x * b.y; acc[0][2] += a.x * b.z; acc[0][3] += a.x * b.w;
            acc[1][0] += a.y * b.x; acc[1][1] += a.y * b.y; acc[1][2] += a.y * b.z; acc[1][3] += a.y * b.w;
            acc[2][0] += a.z * b.x; acc[2][1] += a.z * b.y; acc[2][2] += a.z * b.z; acc[2][3] += a.z * b.w;
            acc[3][0] += a.w * b.x; acc[3][1] += a.w * b.y; acc[3][2] += a.w * b.z; acc[3][3] += a.w * b.w;
        }
        __syncthreads();
    }
    #pragma unroll
    for (int i = 0; i < 4; ++i) {
        const int r = ty * 4 + i;
        #pragma unroll
        for (int j = 0; j < 4; ++j) {
            const int cc = c0 + tx * 4 + j;
            Cp[(size_t)r * ldc + cc] = acc[i][j] + (biasp ? biasp[cc] : 0.f);
        }
    }
}

// ---------------------------------------------------------------------------
// Fused per-step: scores -> softmax -> gates(alpha @ fW + pre_x + ghh) ->
// pointwise LSTM. grid 64 (one block per b), 512 threads; thread t owns d=t.
// ---------------------------------------------------------------------------
__global__ __launch_bounds__(512) void k_fused(
    const float* __restrict__ u_hs,
    const float* __restrict__ A_w, const float* __restrict__ A_b,
    const float* __restrict__ wahp,  // [2][64][512]
    const float* __restrict__ ghhp,  // [2][64][2048]
    const float* __restrict__ pre_x, // [1920][2048] incl. ih_b+hh_b
    const float* __restrict__ fW,    // [64*49][2048]
    float* __restrict__ h_cur, float* __restrict__ c_cur,
    float* __restrict__ Hall, float* __restrict__ alphas,
    int s)
{
    const int b = blockIdx.x;
    const int tid = threadIdx.x;
    const int lane = tid & 63, wid = tid >> 6;
    __shared__ float wah_l[512];
    __shared__ float awl[512];
    __shared__ float red[64];
    __shared__ float al[64];

    wah_l[tid] = wahp[b * 512 + tid] + wahp[32768 + b * 512 + tid];
    awl[tid] = A_w[tid];
    __syncthreads();

    // scores: 8 waves over 49 rows; lane-strided 8 elems each
    for (int n = wid; n < NN; n += 8) {
        const float* up = u_hs + (size_t)(b * NN + n) * 512;
        float acc = 0.f;
        #pragma unroll
        for (int i = 0; i < 8; ++i) {
            const int a = lane + i * 64;
            acc += awl[a] * fast_tanh(up[a] + wah_l[a]);
        }
        #pragma unroll
        for (int m = 32; m; m >>= 1) acc += __shfl_xor(acc, m, 64);
        if (lane == 0) red[n] = acc + A_b[0];
    }
    __syncthreads();

    // softmax over 49 in wave 0
    if (tid < 64) {
        const float sc = (tid < NN) ? red[tid] : -1e30f;
        float mx = sc;
        #pragma unroll
        for (int m = 32; m; m >>= 1) mx = fmaxf(mx, __shfl_xor(mx, m, 64));
        float e = (tid < NN) ? __expf(sc - mx) : 0.f;
        float sum = e;
        #pragma unroll
        for (int m = 32; m; m >>= 1) sum += __shfl_xor(sum, m, 64);
        const float av = e / sum;
        al[tid] = av;
        if (tid < NN)
            alphas[(size_t)b * (TT * NN) + (size_t)s * NN + tid] = av;
    }
    __syncthreads();

    // gates: thread t owns d=t across the 4 gate quadrants
    const int d = tid;
    const float* px = pre_x + (size_t)(s * 64 + b) * 2048;
    const float* g0 = ghhp + (size_t)b * 2048;
    const float* g1 = ghhp + 131072 + (size_t)b * 2048;
    float ai = px[d]        + g0[d]        + g1[d];
    float af = px[512 + d]  + g0[512 + d]  + g1[512 + d];
    float ag = px[1024 + d] + g0[1024 + d] + g1[1024 + d];
    float ao = px[1536 + d] + g0[1536 + d] + g1[1536 + d];
    const float* fb = fW + (size_t)b * NN * 2048;
    #pragma unroll 7
    for (int n = 0; n < NN; ++n) {
        const float w = al[n];
        const float* base = fb + (size_t)n * 2048;
        ai += w * base[d];
        af += w * base[512 + d];
        ag += w * base[1024 + d];
        ao += w * base[1536 + d];
    }
    const float ig = sigmoidf(ai);
    const float fg = sigmoidf(af);
    const float gg = fast_tanh(ag);
    const float og = sigmoidf(ao);
    const float cv = fg * c_cur[b * 512 + d] + ig * gg;
    const float hv = og * fast_tanh(cv);
    c_cur[b * 512 + d] = cv;
    h_cur[b * 512 + d] = hv;
    Hall[(size_t)(s * 64 + b) * 512 + d] = hv;
}

// ---------------------------------------------------------------------------
extern "C" void kernel_launch(void* const* d_in, const int* in_sizes, int n_in,
                              void* d_out, int out_size, void* d_ws, size_t ws_size,
                              hipStream_t stream)
{
    const float* features = (const float*)d_in[0];
    const int*   captions = (const int*)d_in[1];
    const float* emb      = (const float*)d_in[2];
    const float* U_w      = (const float*)d_in[3];
    const float* U_b      = (const float*)d_in[4];
    const float* W_w      = (const float*)d_in[5];
    const float* W_b      = (const float*)d_in[6];
    const float* A_w      = (const float*)d_in[7];
    const float* A_b      = (const float*)d_in[8];
    const float* iH_w     = (const float*)d_in[9];
    const float* iH_b     = (const float*)d_in[10];
    const float* iC_w     = (const float*)d_in[11];
    const float* iC_b     = (const float*)d_in[12];
    const float* ih_w     = (const float*)d_in[13];
    const float* ih_b     = (const float*)d_in[14];
    const float* hh_w     = (const float*)d_in[15];
    const float* hh_b     = (const float*)d_in[16];
    const float* fcn_w    = (const float*)d_in[17];
    const float* fcn_b    = (const float*)d_in[18];

    float* out    = (float*)d_out;
    float* alphas = out + (size_t)B * TT * VOC;

    float* ws     = (float*)d_ws;
    float* fW     = ws;                       // 3136*2048 = 6,422,528
    float* u_hs   = fW + 6422528;             // 3136*512  = 1,605,632
    float* pre_x  = u_hs + 1605632;           // 1920*2048 = 3,932,160
    float* Hall   = pre_x + 3932160;          // 1920*512  = 983,040
    float* mean_f = Hall + 983040;            // 131,072
    float* h_cur  = mean_f + 131072;          // 32,768
    float* c_cur  = h_cur + 32768;            // 32,768
    float* wahp   = c_cur + 32768;            // 2*64*512  = 65,536
    float* ghhp   = wahp + 65536;             // 2*64*2048 = 262,144
    float* embeds = ghhp + 262144;            // 1920*300  = 576,000
    float* bias2  = embeds + 576000;          // 2,048
    float* pbuf   = fW;                       // alias: init partials (dead before fW GEMM)

    // init hidden state (split-K, fully parallel)
    k_mean<<<64, 256, 0, stream>>>(features, mean_f);
    k_init_partial<<<dim3(16, 16), 256, 0, stream>>>(mean_f, iH_w, iC_w, pbuf);
    k_init_reduce<<<256, 256, 0, stream>>>(pbuf, iH_b, iC_b, h_cur, c_cur);

    // hoisted precomputes
    k_embed<<<1920, 256, 0, stream>>>(captions, emb, embeds);
    k_bias2<<<8, 256, 0, stream>>>(ih_b, hh_b, bias2);
    // u_hs = features @ U_w^T + U_b                 [3136, 512]
    mfma_nt<<<dim3(4, 25), 512, 0, stream>>>(features, ENC, U_w, ENC, U_b, u_hs, ATT, B * NN, ATT, ENC, 0);
    // pre_x = embeds @ ih_w[:, :300]^T + (ih_b+hh_b) [1920, 2048]
    mfma_nt<<<dim3(16, 15), 512, 0, stream>>>(embeds, EMB, ih_w, 2348, bias2, pre_x, 2048, TT * B, 2048, EMB, 0);
    // fW = features @ ih_w[:, 300:2348]^T            [3136, 2048]
    mfma_nt<<<dim3(16, 25), 512, 0, stream>>>(features, ENC, ih_w + 300, 2348, nullptr, fW, 2048, B * NN, 2048, ENC, 0);

    // recurrence: 2 launches per step
    k_hw2<<<dim3(40, 2), 256, 0, stream>>>(h_cur, W_w, W_b, hh_w, wahp, ghhp);
    for (int s = 0; s < TT; ++s) {
        k_fused<<<64, 512, 0, stream>>>(u_hs, A_w, A_b, wahp, ghhp, pre_x, fW,
                                        h_cur, c_cur, Hall, alphas, s);
        if (s < TT - 1)
            k_hw2<<<dim3(40, 2), 256, 0, stream>>>(h_cur, W_w, W_b, hh_w, wahp, ghhp);
    }

    // batched output projection
    mfma_nt<<<dim3(79, 15), 512, 0, stream>>>(Hall, DEC, fcn_w, DEC, fcn_b, out, VOC,
                                              TT * B, VOC, DEC, 1);
}